// Round 4
// baseline (497.702 us; speedup 1.0000x reference)
//
#include <hip/hip_runtime.h>
#include <hip/hip_bf16.h>

typedef __attribute__((ext_vector_type(8))) short bf16x8;
typedef __attribute__((ext_vector_type(4))) float f32x4;

#define T_SZ 2048
#define C_SZ 1024
#define H_SZ 16
#define D_SZ 64
#define N_SZ 3072
#define M_SZ 8192

__device__ __forceinline__ unsigned short f2bf(float f) {
    unsigned int u = __float_as_uint(f);
    unsigned int r = (u + 0x7fffu + ((u >> 16) & 1u)) >> 16;
    return (unsigned short)r;
}

__device__ __forceinline__ void gload_lds16(const void* g, void* l) {
    __builtin_amdgcn_global_load_lds(
        (const __attribute__((address_space(1))) unsigned int*)g,
        (__attribute__((address_space(3))) unsigned int*)l, 16, 0, 0);
}

// ---- x fp32 -> bf16 ----
__global__ __launch_bounds__(256) void k_convert(const float* __restrict__ in,
                                                 unsigned short* __restrict__ out, int n4) {
    int i = blockIdx.x * 256 + threadIdx.x;
    if (i >= n4) return;
    float4 v = ((const float4*)in)[i];
    ushort4 u;
    u.x = f2bf(v.x); u.y = f2bf(v.y); u.z = f2bf(v.z); u.w = f2bf(v.w);
    ((ushort4*)out)[i] = u;
}

// ---- w [1024][3072] fp32 -> wt [3072][1024] bf16 ----
__global__ __launch_bounds__(256) void k_transpose(const float* __restrict__ w,
                                                   unsigned short* __restrict__ wt) {
    __shared__ float tile[32][33];
    const int nb = blockIdx.x * 32;
    const int kb = blockIdx.y * 32;
    const int tx = threadIdx.x & 31;
    const int ty = threadIdx.x >> 5;
#pragma unroll
    for (int i = 0; i < 32; i += 8)
        tile[ty + i][tx] = w[(size_t)(kb + ty + i) * N_SZ + nb + tx];
    __syncthreads();
#pragma unroll
    for (int i = 0; i < 32; i += 8)
        wt[(size_t)(nb + ty + i) * C_SZ + kb + tx] = f2bf(tile[tx][ty + i]);
}

// ---- QKV GEMM: writes Q,K as [B,H,T,D]; V transposed as [B,H,D,T] ----
__global__ __launch_bounds__(256) void k_qkv_gemm(const unsigned short* __restrict__ A,
                                                  const unsigned short* __restrict__ Bt,
                                                  unsigned short* __restrict__ Qb,
                                                  unsigned short* __restrict__ Kb,
                                                  unsigned short* __restrict__ Vtb) {
    __shared__ __align__(16) unsigned short As[128 * 32];
    __shared__ __align__(16) unsigned short Bs[128 * 32];
    const int tid = threadIdx.x;
    const int lane = tid & 63, wid = tid >> 6;
    const int wm = wid & 1, wn = wid >> 1;
    const int row0 = blockIdx.x * 128;
    const int col0 = blockIdx.y * 128;
    f32x4 acc[4][4] = {};
    const int c0 = 2 * wid, c1 = 2 * wid + 1;
    const int lr = lane >> 2, lk = (lane & 3) * 8;
    const int l15 = lane & 15, lg = lane >> 4;

    for (int kt = 0; kt < 1024; kt += 32) {
        __syncthreads();
        gload_lds16(A + (size_t)(row0 + c0 * 16 + lr) * 1024 + kt + lk, As + c0 * 512);
        gload_lds16(A + (size_t)(row0 + c1 * 16 + lr) * 1024 + kt + lk, As + c1 * 512);
        gload_lds16(Bt + (size_t)(col0 + c0 * 16 + lr) * 1024 + kt + lk, Bs + c0 * 512);
        gload_lds16(Bt + (size_t)(col0 + c1 * 16 + lr) * 1024 + kt + lk, Bs + c1 * 512);
        __syncthreads();
        bf16x8 af[4], bfr[4];
#pragma unroll
        for (int m = 0; m < 4; ++m)
            af[m] = *(const bf16x8*)&As[(wm * 64 + m * 16 + l15) * 32 + lg * 8];
#pragma unroll
        for (int n = 0; n < 4; ++n)
            bfr[n] = *(const bf16x8*)&Bs[(wn * 64 + n * 16 + l15) * 32 + lg * 8];
#pragma unroll
        for (int m = 0; m < 4; ++m)
#pragma unroll
            for (int n = 0; n < 4; ++n)
                acc[m][n] = __builtin_amdgcn_mfma_f32_16x16x32_bf16(af[m], bfr[n], acc[m][n], 0, 0, 0);
    }

    const int sel = col0 >> 10;
    if (sel < 2) {
        unsigned short* dst = (sel == 0) ? Qb : Kb;
#pragma unroll
        for (int m = 0; m < 4; ++m) {
#pragma unroll
            for (int n = 0; n < 4; ++n) {
                int col = col0 + wn * 64 + n * 16 + l15;
                int cc = col & 1023;
                int h = cc >> 6, d = cc & 63;
#pragma unroll
                for (int i = 0; i < 4; ++i) {
                    int row = row0 + wm * 64 + m * 16 + lg * 4 + i;
                    int b = row >> 11, t = row & 2047;
                    size_t idx = ((size_t)(b * 16 + h) * 2048 + t) * 64 + d;
                    dst[idx] = f2bf(acc[m][n][i]);
                }
            }
        }
    } else {
        // V: write transposed [B,H,D,T]; 4 consecutive t packed per store
#pragma unroll
        for (int m = 0; m < 4; ++m) {
#pragma unroll
            for (int n = 0; n < 4; ++n) {
                int cc = (col0 + wn * 64 + n * 16 + l15) & 1023;
                int h = cc >> 6, d = cc & 63;
                int row = row0 + wm * 64 + m * 16 + lg * 4;  // t0, 4 contiguous
                int b = row >> 11, t = row & 2047;
                ushort4 u;
                u.x = f2bf(acc[m][n][0]); u.y = f2bf(acc[m][n][1]);
                u.z = f2bf(acc[m][n][2]); u.w = f2bf(acc[m][n][3]);
                size_t idx = ((size_t)(b * 16 + h) * 64 + d) * 2048 + t;
                *(ushort4*)&Vtb[idx] = u;
            }
        }
    }
}

__device__ __forceinline__ void load_k(const unsigned short* __restrict__ Kp, int k0,
                                       int l15, int lg, bf16x8 kf[4][2]) {
#pragma unroll
    for (int ct = 0; ct < 4; ++ct)
#pragma unroll
        for (int kh = 0; kh < 2; ++kh)
            kf[ct][kh] = *(const bf16x8*)&Kp[(size_t)(k0 + ct * 16 + l15) * 64 + kh * 32 + lg * 8];
}

// ---- causal flash attention: 128 q-rows/block, 4 independent waves, no barriers ----
__global__ __launch_bounds__(256) void k_attn(const unsigned short* __restrict__ Qb,
                                              const unsigned short* __restrict__ Kb,
                                              const unsigned short* __restrict__ Vt,
                                              float* __restrict__ out) {
    const int qb = 15 - blockIdx.x;  // longest blocks dispatched first
    const int bh = blockIdx.y;
    const int bb = bh >> 4, hh = bh & 15;
    const unsigned short* Qp = Qb + (size_t)bh * T_SZ * D_SZ;
    const unsigned short* Kp = Kb + (size_t)bh * T_SZ * D_SZ;
    const unsigned short* Vp = Vt + (size_t)bh * T_SZ * D_SZ;  // [D=64][T=2048]
    const int tid = threadIdx.x, lane = tid & 63, wid = tid >> 6;
    const int l15 = lane & 15, lg = lane >> 4;
    const int rga0 = qb * 128 + wid * 32;

    __shared__ __align__(16) unsigned short Pl[4][2][16][72];  // per-wave P, padded

    bf16x8 qf[2][2];
#pragma unroll
    for (int rg = 0; rg < 2; ++rg)
#pragma unroll
        for (int kh = 0; kh < 2; ++kh)
            qf[rg][kh] = *(const bf16x8*)&Qp[(size_t)(rga0 + rg * 16 + l15) * 64 + kh * 32 + lg * 8];

    f32x4 oacc[2][4] = {};
    float mrow[2][4], lrow[2][4];
#pragma unroll
    for (int rg = 0; rg < 2; ++rg)
#pragma unroll
        for (int i = 0; i < 4; ++i) { mrow[rg][i] = -1e30f; lrow[rg][i] = 0.f; }

    const int kb_max = 2 * qb + 1;
    const float scale = 0.125f;

    bf16x8 kf[4][2];
    load_k(Kp, 0, l15, lg, kf);

    for (int kb = 0; kb <= kb_max; ++kb) {
        const int k0 = kb * 64;
        bool act[2];
        f32x4 s[2][4];
#pragma unroll
        for (int rg = 0; rg < 2; ++rg) {
            const int rga = rga0 + rg * 16;
            act[rg] = (k0 <= rga + 15);
            if (!act[rg]) continue;
#pragma unroll
            for (int ct = 0; ct < 4; ++ct) {
                f32x4 a = {};
#pragma unroll
                for (int kh = 0; kh < 2; ++kh)
                    a = __builtin_amdgcn_mfma_f32_16x16x32_bf16(qf[rg][kh], kf[ct][kh], a, 0, 0, 0);
                s[rg][ct] = a;
            }
        }
        // V fragments for this block (latency hidden under softmax)
        bf16x8 vf[4][2];
#pragma unroll
        for (int ct = 0; ct < 4; ++ct)
#pragma unroll
            for (int kh = 0; kh < 2; ++kh)
                vf[ct][kh] = *(const bf16x8*)&Vp[(size_t)(ct * 16 + l15) * 2048 + k0 + kh * 32 + lg * 8];
        if (kb < kb_max) load_k(Kp, k0 + 64, l15, lg, kf);  // prefetch next K

#pragma unroll
        for (int rg = 0; rg < 2; ++rg) {
            if (!act[rg]) continue;
            const int rga = rga0 + rg * 16;
            if (k0 + 63 > rga) {
#pragma unroll
                for (int ct = 0; ct < 4; ++ct) {
                    const int key = k0 + ct * 16 + l15;
#pragma unroll
                    for (int i = 0; i < 4; ++i) {
                        const int qrow = rga + lg * 4 + i;
                        s[rg][ct][i] = (key <= qrow) ? s[rg][ct][i] * scale : -1e30f;
                    }
                }
            } else {
#pragma unroll
                for (int ct = 0; ct < 4; ++ct)
#pragma unroll
                    for (int i = 0; i < 4; ++i) s[rg][ct][i] *= scale;
            }
#pragma unroll
            for (int i = 0; i < 4; ++i) {
                float rmax = fmaxf(fmaxf(s[rg][0][i], s[rg][1][i]), fmaxf(s[rg][2][i], s[rg][3][i]));
                rmax = fmaxf(rmax, __shfl_xor(rmax, 1));
                rmax = fmaxf(rmax, __shfl_xor(rmax, 2));
                rmax = fmaxf(rmax, __shfl_xor(rmax, 4));
                rmax = fmaxf(rmax, __shfl_xor(rmax, 8));
                float mnew = fmaxf(mrow[rg][i], rmax);
                float sc = __expf(mrow[rg][i] - mnew);
                float rsum = 0.f;
#pragma unroll
                for (int ct = 0; ct < 4; ++ct) {
                    float pv = __expf(s[rg][ct][i] - mnew);
                    s[rg][ct][i] = pv;
                    rsum += pv;
                }
                rsum += __shfl_xor(rsum, 1);
                rsum += __shfl_xor(rsum, 2);
                rsum += __shfl_xor(rsum, 4);
                rsum += __shfl_xor(rsum, 8);
                lrow[rg][i] = lrow[rg][i] * sc + rsum;
                mrow[rg][i] = mnew;
#pragma unroll
                for (int ct = 0; ct < 4; ++ct) oacc[rg][ct][i] *= sc;
            }
            // P -> per-wave LDS (C-layout write, A-layout read)
#pragma unroll
            for (int ct = 0; ct < 4; ++ct)
#pragma unroll
                for (int i = 0; i < 4; ++i)
                    Pl[wid][rg][lg * 4 + i][ct * 16 + l15] = f2bf(s[rg][ct][i]);
        }

        // O += P V
#pragma unroll
        for (int kh = 0; kh < 2; ++kh) {
            bf16x8 pf[2];
#pragma unroll
            for (int rg = 0; rg < 2; ++rg)
                if (act[rg]) pf[rg] = *(const bf16x8*)&Pl[wid][rg][l15][kh * 32 + lg * 8];
#pragma unroll
            for (int ct = 0; ct < 4; ++ct)
#pragma unroll
                for (int rg = 0; rg < 2; ++rg) {
                    if (!act[rg]) continue;
                    oacc[rg][ct] = __builtin_amdgcn_mfma_f32_16x16x32_bf16(pf[rg], vf[ct][kh], oacc[rg][ct], 0, 0, 0);
                }
        }
    }

#pragma unroll
    for (int rg = 0; rg < 2; ++rg) {
        const int rga = rga0 + rg * 16;
#pragma unroll
        for (int ct = 0; ct < 4; ++ct)
#pragma unroll
            for (int i = 0; i < 4; ++i) {
                const int qrow = rga + lg * 4 + i;
                out[((size_t)bb * T_SZ + qrow) * C_SZ + hh * 64 + ct * 16 + l15] =
                    oacc[rg][ct][i] / lrow[rg][i];
            }
    }
}

extern "C" void kernel_launch(void* const* d_in, const int* in_sizes, int n_in,
                              void* d_out, int out_size, void* d_ws, size_t ws_size,
                              hipStream_t stream) {
    const float* x = (const float*)d_in[0];
    const float* w = (const float*)d_in[1];
    float* out = (float*)d_out;
    char* ws = (char*)d_ws;
    unsigned short* xb  = (unsigned short*)(ws);
    unsigned short* wtb = (unsigned short*)(ws + 16777216);
    unsigned short* Qb  = (unsigned short*)(ws + 16777216 + 6291456);
    unsigned short* Kb  = (unsigned short*)(ws + 16777216 + 6291456 + 16777216);
    unsigned short* Vtb = (unsigned short*)(ws + 16777216 + 6291456 + 2 * 16777216);

    k_convert<<<8192, 256, 0, stream>>>(x, xb, 2097152);
    k_transpose<<<dim3(96, 32), 256, 0, stream>>>(w, wtb);
    k_qkv_gemm<<<dim3(64, 24), 256, 0, stream>>>(xb, wtb, Qb, Kb, Vtb);
    k_attn<<<dim3(16, 64), 256, 0, stream>>>(Qb, Kb, Vtb, out);
}

// Round 5
// 429.637 us; speedup vs baseline: 1.1584x; 1.1584x over previous
//
#include <hip/hip_runtime.h>
#include <hip/hip_bf16.h>

typedef __attribute__((ext_vector_type(8))) short bf16x8;
typedef __attribute__((ext_vector_type(4))) float f32x4;

#define T_SZ 2048
#define C_SZ 1024
#define H_SZ 16
#define D_SZ 64
#define N_SZ 3072
#define M_SZ 8192

// 0.125 (D^-0.5) * log2(e): folded into Q so softmax runs in exp2 domain
#define Q_SCALE 0.18033688011112042f

__device__ __forceinline__ unsigned short f2bf(float f) {
    unsigned int u = __float_as_uint(f);
    unsigned int r = (u + 0x7fffu + ((u >> 16) & 1u)) >> 16;
    return (unsigned short)r;
}

__device__ __forceinline__ void gload_lds16(const void* g, void* l) {
    __builtin_amdgcn_global_load_lds(
        (const __attribute__((address_space(1))) unsigned int*)g,
        (__attribute__((address_space(3))) unsigned int*)l, 16, 0, 0);
}

// ---- x fp32 -> bf16 ----
__global__ __launch_bounds__(256) void k_convert(const float* __restrict__ in,
                                                 unsigned short* __restrict__ out, int n4) {
    int i = blockIdx.x * 256 + threadIdx.x;
    if (i >= n4) return;
    float4 v = ((const float4*)in)[i];
    ushort4 u;
    u.x = f2bf(v.x); u.y = f2bf(v.y); u.z = f2bf(v.z); u.w = f2bf(v.w);
    ((ushort4*)out)[i] = u;
}

// ---- w [1024][3072] fp32 -> wt [3072][1024] bf16 ----
__global__ __launch_bounds__(256) void k_transpose(const float* __restrict__ w,
                                                   unsigned short* __restrict__ wt) {
    __shared__ float tile[32][33];
    const int nb = blockIdx.x * 32;
    const int kb = blockIdx.y * 32;
    const int tx = threadIdx.x & 31;
    const int ty = threadIdx.x >> 5;
#pragma unroll
    for (int i = 0; i < 32; i += 8)
        tile[ty + i][tx] = w[(size_t)(kb + ty + i) * N_SZ + nb + tx];
    __syncthreads();
#pragma unroll
    for (int i = 0; i < 32; i += 8)
        wt[(size_t)(nb + ty + i) * C_SZ + kb + tx] = f2bf(tile[tx][ty + i]);
}

// ---- QKV GEMM: Q (pre-scaled) & K as [B,H,T,D]; V transposed as [B,H,D,T] ----
// flat grid 1536, XCD-swizzled: each XCD keeps one A row-panel across all 24 col-panels
__global__ __launch_bounds__(256) void k_qkv_gemm(const unsigned short* __restrict__ A,
                                                  const unsigned short* __restrict__ Bt,
                                                  unsigned short* __restrict__ Qb,
                                                  unsigned short* __restrict__ Kb,
                                                  unsigned short* __restrict__ Vtb) {
    __shared__ __align__(16) unsigned short As[128 * 32];
    __shared__ __align__(16) unsigned short Bs[128 * 32];
    const int id = blockIdx.x;
    const int gx = id & 7, jj = id >> 3;      // 8 XCDs round-robin
    const int yblk = jj % 24;                  // col panel (B reuse streamed)
    const int xblk = gx + 8 * (jj / 24);       // row panel pinned per XCD
    const int tid = threadIdx.x;
    const int lane = tid & 63, wid = tid >> 6;
    const int wm = wid & 1, wn = wid >> 1;
    const int row0 = xblk * 128;
    const int col0 = yblk * 128;
    f32x4 acc[4][4] = {};
    const int c0 = 2 * wid, c1 = 2 * wid + 1;
    const int lr = lane >> 2, lk = (lane & 3) * 8;
    const int l15 = lane & 15, lg = lane >> 4;

    for (int kt = 0; kt < 1024; kt += 32) {
        __syncthreads();
        gload_lds16(A + (size_t)(row0 + c0 * 16 + lr) * 1024 + kt + lk, As + c0 * 512);
        gload_lds16(A + (size_t)(row0 + c1 * 16 + lr) * 1024 + kt + lk, As + c1 * 512);
        gload_lds16(Bt + (size_t)(col0 + c0 * 16 + lr) * 1024 + kt + lk, Bs + c0 * 512);
        gload_lds16(Bt + (size_t)(col0 + c1 * 16 + lr) * 1024 + kt + lk, Bs + c1 * 512);
        __syncthreads();
        bf16x8 af[4], bfr[4];
#pragma unroll
        for (int m = 0; m < 4; ++m)
            af[m] = *(const bf16x8*)&As[(wm * 64 + m * 16 + l15) * 32 + lg * 8];
#pragma unroll
        for (int n = 0; n < 4; ++n)
            bfr[n] = *(const bf16x8*)&Bs[(wn * 64 + n * 16 + l15) * 32 + lg * 8];
#pragma unroll
        for (int m = 0; m < 4; ++m)
#pragma unroll
            for (int n = 0; n < 4; ++n)
                acc[m][n] = __builtin_amdgcn_mfma_f32_16x16x32_bf16(af[m], bfr[n], acc[m][n], 0, 0, 0);
    }

    const int sel = col0 >> 10;
    if (sel < 2) {
        unsigned short* dst = (sel == 0) ? Qb : Kb;
        const float qs = (sel == 0) ? Q_SCALE : 1.0f;
#pragma unroll
        for (int m = 0; m < 4; ++m) {
#pragma unroll
            for (int n = 0; n < 4; ++n) {
                int cc = (col0 + wn * 64 + n * 16 + l15) & 1023;
                int h = cc >> 6, d = cc & 63;
#pragma unroll
                for (int i = 0; i < 4; ++i) {
                    int row = row0 + wm * 64 + m * 16 + lg * 4 + i;
                    int b = row >> 11, t = row & 2047;
                    size_t idx = ((size_t)(b * 16 + h) * 2048 + t) * 64 + d;
                    dst[idx] = f2bf(acc[m][n][i] * qs);
                }
            }
        }
    } else {
        // V: write transposed [B,H,D,T]; 4 consecutive t packed per store
#pragma unroll
        for (int m = 0; m < 4; ++m) {
#pragma unroll
            for (int n = 0; n < 4; ++n) {
                int cc = (col0 + wn * 64 + n * 16 + l15) & 1023;
                int h = cc >> 6, d = cc & 63;
                int row = row0 + wm * 64 + m * 16 + lg * 4;  // t0, 4 contiguous
                int b = row >> 11, t = row & 2047;
                ushort4 u;
                u.x = f2bf(acc[m][n][0]); u.y = f2bf(acc[m][n][1]);
                u.z = f2bf(acc[m][n][2]); u.w = f2bf(acc[m][n][3]);
                size_t idx = ((size_t)(b * 16 + h) * 64 + d) * 2048 + t;
                *(ushort4*)&Vtb[idx] = u;
            }
        }
    }
}

__device__ __forceinline__ void load_k(const unsigned short* __restrict__ Kp, int k0,
                                       int l15, int lg, bf16x8 kf[4][2]) {
#pragma unroll
    for (int ct = 0; ct < 4; ++ct)
#pragma unroll
        for (int kh = 0; kh < 2; ++kh)
            kf[ct][kh] = *(const bf16x8*)&Kp[(size_t)(k0 + ct * 16 + l15) * 64 + kh * 32 + lg * 8];
}

// ---- causal flash attention: 64 q-rows/block, 4 independent waves (16 rows each) ----
// flat grid 2048, XCD-swizzled: XCD g owns bh in {g, g+8, ...} -> K/V (4MB) L2-resident
__global__ __launch_bounds__(256, 4) void k_attn(const unsigned short* __restrict__ Qb,
                                                 const unsigned short* __restrict__ Kb,
                                                 const unsigned short* __restrict__ Vt,
                                                 float* __restrict__ out) {
    const int id = blockIdx.x;
    const int g = id & 7, j = id >> 3;           // XCD, per-XCD seq
    const int qb = 31 - (j & 31);                // longest first within XCD stream
    const int bh = g + ((j >> 5) << 3);          // 8 bh per XCD
    const int bb = bh >> 4, hh = bh & 15;
    const unsigned short* Qp = Qb + (size_t)bh * T_SZ * D_SZ;
    const unsigned short* Kp = Kb + (size_t)bh * T_SZ * D_SZ;
    const unsigned short* Vp = Vt + (size_t)bh * T_SZ * D_SZ;  // [D=64][T=2048]
    const int tid = threadIdx.x, lane = tid & 63, wid = tid >> 6;
    const int l15 = lane & 15, lg = lane >> 4;
    const int rga = qb * 64 + wid * 16;

    __shared__ __align__(16) unsigned short Pl[4][16][72];  // per-wave P, padded

    bf16x8 qf[2];
#pragma unroll
    for (int kh = 0; kh < 2; ++kh)
        qf[kh] = *(const bf16x8*)&Qp[(size_t)(rga + l15) * 64 + kh * 32 + lg * 8];

    f32x4 oacc[4] = {};
    float mrow[4] = {-1e30f, -1e30f, -1e30f, -1e30f};
    float lrow[4] = {0.f, 0.f, 0.f, 0.f};

    bf16x8 kf[4][2];
    load_k(Kp, 0, l15, lg, kf);

    for (int kb = 0; kb <= qb; ++kb) {
        const int k0 = kb * 64;
        // V fragments issued first: latency hidden under QK^T + softmax
        bf16x8 vf[4][2];
#pragma unroll
        for (int ct = 0; ct < 4; ++ct)
#pragma unroll
            for (int kh = 0; kh < 2; ++kh)
                vf[ct][kh] = *(const bf16x8*)&Vp[(size_t)(ct * 16 + l15) * 2048 + k0 + kh * 32 + lg * 8];

        const bool act = (k0 <= rga + 15);  // wave-uniform
        f32x4 s[4];
        if (act) {
#pragma unroll
            for (int ct = 0; ct < 4; ++ct) {
                f32x4 a = {};
#pragma unroll
                for (int kh = 0; kh < 2; ++kh)
                    a = __builtin_amdgcn_mfma_f32_16x16x32_bf16(qf[kh], kf[ct][kh], a, 0, 0, 0);
                s[ct] = a;
            }
        }
        if (kb < qb) load_k(Kp, k0 + 64, l15, lg, kf);  // prefetch next K

        if (act) {
            if (k0 + 63 > rga) {  // diagonal region: causal mask (Q pre-scaled, exp2 domain)
#pragma unroll
                for (int ct = 0; ct < 4; ++ct) {
                    const int key = k0 + ct * 16 + l15;
#pragma unroll
                    for (int i = 0; i < 4; ++i) {
                        const int qrow = rga + lg * 4 + i;
                        s[ct][i] = (key <= qrow) ? s[ct][i] : -1e30f;
                    }
                }
            }
#pragma unroll
            for (int i = 0; i < 4; ++i) {
                float rmax = fmaxf(fmaxf(s[0][i], s[1][i]), fmaxf(s[2][i], s[3][i]));
                rmax = fmaxf(rmax, __shfl_xor(rmax, 1));
                rmax = fmaxf(rmax, __shfl_xor(rmax, 2));
                rmax = fmaxf(rmax, __shfl_xor(rmax, 4));
                rmax = fmaxf(rmax, __shfl_xor(rmax, 8));
                float mnew = fmaxf(mrow[i], rmax);
                float sc = __builtin_amdgcn_exp2f(mrow[i] - mnew);
                float rsum = 0.f;
#pragma unroll
                for (int ct = 0; ct < 4; ++ct) {
                    float pv = __builtin_amdgcn_exp2f(s[ct][i] - mnew);
                    s[ct][i] = pv;
                    rsum += pv;
                }
                rsum += __shfl_xor(rsum, 1);
                rsum += __shfl_xor(rsum, 2);
                rsum += __shfl_xor(rsum, 4);
                rsum += __shfl_xor(rsum, 8);
                lrow[i] = lrow[i] * sc + rsum;
                mrow[i] = mnew;
#pragma unroll
                for (int ct = 0; ct < 4; ++ct) oacc[ct][i] *= sc;
            }
            // P -> per-wave LDS (C-layout write, A-layout read)
#pragma unroll
            for (int ct = 0; ct < 4; ++ct)
#pragma unroll
                for (int i = 0; i < 4; ++i)
                    Pl[wid][lg * 4 + i][ct * 16 + l15] = f2bf(s[ct][i]);

            // O += P V
#pragma unroll
            for (int kh = 0; kh < 2; ++kh) {
                const bf16x8 pf = *(const bf16x8*)&Pl[wid][l15][kh * 32 + lg * 8];
#pragma unroll
                for (int ct = 0; ct < 4; ++ct)
                    oacc[ct] = __builtin_amdgcn_mfma_f32_16x16x32_bf16(pf, vf[ct][kh], oacc[ct], 0, 0, 0);
            }
        }
    }

#pragma unroll
    for (int ct = 0; ct < 4; ++ct) {
#pragma unroll
        for (int i = 0; i < 4; ++i) {
            const int qrow = rga + lg * 4 + i;
            out[((size_t)bb * T_SZ + qrow) * C_SZ + hh * 64 + ct * 16 + l15] =
                oacc[ct][i] / lrow[i];
        }
    }
}

extern "C" void kernel_launch(void* const* d_in, const int* in_sizes, int n_in,
                              void* d_out, int out_size, void* d_ws, size_t ws_size,
                              hipStream_t stream) {
    const float* x = (const float*)d_in[0];
    const float* w = (const float*)d_in[1];
    float* out = (float*)d_out;
    char* ws = (char*)d_ws;
    unsigned short* xb  = (unsigned short*)(ws);
    unsigned short* wtb = (unsigned short*)(ws + 16777216);
    unsigned short* Qb  = (unsigned short*)(ws + 16777216 + 6291456);
    unsigned short* Kb  = (unsigned short*)(ws + 16777216 + 6291456 + 16777216);
    unsigned short* Vtb = (unsigned short*)(ws + 16777216 + 6291456 + 2 * 16777216);

    k_convert<<<8192, 256, 0, stream>>>(x, xb, 2097152);
    k_transpose<<<dim3(96, 32), 256, 0, stream>>>(w, wtb);
    k_qkv_gemm<<<1536, 256, 0, stream>>>(xb, wtb, Qb, Kb, Vtb);
    k_attn<<<2048, 256, 0, stream>>>(Qb, Kb, Vtb, out);
}

// Round 6
// 408.161 us; speedup vs baseline: 1.2194x; 1.0526x over previous
//
#include <hip/hip_runtime.h>
#include <hip/hip_bf16.h>

typedef __attribute__((ext_vector_type(8))) short bf16x8;
typedef __attribute__((ext_vector_type(4))) float f32x4;

#define T_SZ 2048
#define C_SZ 1024
#define H_SZ 16
#define D_SZ 64
#define N_SZ 3072
#define M_SZ 8192

// 0.125 (D^-0.5) * log2(e): folded into Q so softmax runs in exp2 domain
#define Q_SCALE 0.18033688011112042f

__device__ __forceinline__ unsigned short f2bf(float f) {
    unsigned int u = __float_as_uint(f);
    unsigned int r = (u + 0x7fffu + ((u >> 16) & 1u)) >> 16;
    return (unsigned short)r;
}

__device__ __forceinline__ void gload_lds16(const void* g, void* l) {
    __builtin_amdgcn_global_load_lds(
        (const __attribute__((address_space(1))) unsigned int*)g,
        (__attribute__((address_space(3))) unsigned int*)l, 16, 0, 0);
}

// ---- x fp32 -> bf16 ----
__global__ __launch_bounds__(256) void k_convert(const float* __restrict__ in,
                                                 unsigned short* __restrict__ out, int n4) {
    int i = blockIdx.x * 256 + threadIdx.x;
    if (i >= n4) return;
    float4 v = ((const float4*)in)[i];
    ushort4 u;
    u.x = f2bf(v.x); u.y = f2bf(v.y); u.z = f2bf(v.z); u.w = f2bf(v.w);
    ((ushort4*)out)[i] = u;
}

// ---- w [1024][3072] fp32 -> wt [3072][1024] bf16 ----
__global__ __launch_bounds__(256) void k_transpose(const float* __restrict__ w,
                                                   unsigned short* __restrict__ wt) {
    __shared__ float tile[32][33];
    const int nb = blockIdx.x * 32;
    const int kb = blockIdx.y * 32;
    const int tx = threadIdx.x & 31;
    const int ty = threadIdx.x >> 5;
#pragma unroll
    for (int i = 0; i < 32; i += 8)
        tile[ty + i][tx] = w[(size_t)(kb + ty + i) * N_SZ + nb + tx];
    __syncthreads();
#pragma unroll
    for (int i = 0; i < 32; i += 8)
        wt[(size_t)(nb + ty + i) * C_SZ + kb + tx] = f2bf(tile[tx][ty + i]);
}

// ---- QKV GEMM: Q (pre-scaled) & K as [B,H,T,D]; V transposed as [B,H,D,T] ----
__global__ __launch_bounds__(256) void k_qkv_gemm(const unsigned short* __restrict__ A,
                                                  const unsigned short* __restrict__ Bt,
                                                  unsigned short* __restrict__ Qb,
                                                  unsigned short* __restrict__ Kb,
                                                  unsigned short* __restrict__ Vtb) {
    __shared__ __align__(16) unsigned short As[128 * 32];
    __shared__ __align__(16) unsigned short Bs[128 * 32];
    const int id = blockIdx.x;
    const int gx = id & 7, jj = id >> 3;      // 8 XCDs round-robin
    const int yblk = jj % 24;                  // col panel (B reuse streamed)
    const int xblk = gx + 8 * (jj / 24);       // row panel pinned per XCD
    const int tid = threadIdx.x;
    const int lane = tid & 63, wid = tid >> 6;
    const int wm = wid & 1, wn = wid >> 1;
    const int row0 = xblk * 128;
    const int col0 = yblk * 128;
    f32x4 acc[4][4] = {};
    const int c0 = 2 * wid, c1 = 2 * wid + 1;
    const int lr = lane >> 2, lk = (lane & 3) * 8;
    const int l15 = lane & 15, lg = lane >> 4;

    for (int kt = 0; kt < 1024; kt += 32) {
        __syncthreads();
        gload_lds16(A + (size_t)(row0 + c0 * 16 + lr) * 1024 + kt + lk, As + c0 * 512);
        gload_lds16(A + (size_t)(row0 + c1 * 16 + lr) * 1024 + kt + lk, As + c1 * 512);
        gload_lds16(Bt + (size_t)(col0 + c0 * 16 + lr) * 1024 + kt + lk, Bs + c0 * 512);
        gload_lds16(Bt + (size_t)(col0 + c1 * 16 + lr) * 1024 + kt + lk, Bs + c1 * 512);
        __syncthreads();
        bf16x8 af[4], bfr[4];
#pragma unroll
        for (int m = 0; m < 4; ++m)
            af[m] = *(const bf16x8*)&As[(wm * 64 + m * 16 + l15) * 32 + lg * 8];
#pragma unroll
        for (int n = 0; n < 4; ++n)
            bfr[n] = *(const bf16x8*)&Bs[(wn * 64 + n * 16 + l15) * 32 + lg * 8];
#pragma unroll
        for (int m = 0; m < 4; ++m)
#pragma unroll
            for (int n = 0; n < 4; ++n)
                acc[m][n] = __builtin_amdgcn_mfma_f32_16x16x32_bf16(af[m], bfr[n], acc[m][n], 0, 0, 0);
    }

    const int sel = col0 >> 10;
    if (sel < 2) {
        unsigned short* dst = (sel == 0) ? Qb : Kb;
        const float qs = (sel == 0) ? Q_SCALE : 1.0f;
#pragma unroll
        for (int m = 0; m < 4; ++m) {
#pragma unroll
            for (int n = 0; n < 4; ++n) {
                int cc = (col0 + wn * 64 + n * 16 + l15) & 1023;
                int h = cc >> 6, d = cc & 63;
#pragma unroll
                for (int i = 0; i < 4; ++i) {
                    int row = row0 + wm * 64 + m * 16 + lg * 4 + i;
                    int b = row >> 11, t = row & 2047;
                    size_t idx = ((size_t)(b * 16 + h) * 2048 + t) * 64 + d;
                    dst[idx] = f2bf(acc[m][n][i] * qs);
                }
            }
        }
    } else {
        // V: write transposed [B,H,D,T]; 4 consecutive t packed per store
#pragma unroll
        for (int m = 0; m < 4; ++m) {
#pragma unroll
            for (int n = 0; n < 4; ++n) {
                int cc = (col0 + wn * 64 + n * 16 + l15) & 1023;
                int h = cc >> 6, d = cc & 63;
                int row = row0 + wm * 64 + m * 16 + lg * 4;  // t0, 4 contiguous
                int b = row >> 11, t = row & 2047;
                ushort4 u;
                u.x = f2bf(acc[m][n][0]); u.y = f2bf(acc[m][n][1]);
                u.z = f2bf(acc[m][n][2]); u.w = f2bf(acc[m][n][3]);
                size_t idx = ((size_t)(b * 16 + h) * 64 + d) * 2048 + t;
                *(ushort4*)&Vtb[idx] = u;
            }
        }
    }
}

// ---- causal flash attention, swapped-QK^T softmax ----
// 64 q-rows/block, 4 independent waves (16 rows each), no barriers.
// XCD-swizzled grid: XCD g owns bh in {g, g+8, ...} -> K/V (4MB) L2-resident.
__global__ __launch_bounds__(256, 3) void k_attn(const unsigned short* __restrict__ Qb,
                                                 const unsigned short* __restrict__ Kb,
                                                 const unsigned short* __restrict__ Vt,
                                                 float* __restrict__ out) {
    const int id = blockIdx.x;
    const int g = id & 7, j = id >> 3;           // XCD, per-XCD seq
    const int qb = 31 - (j & 31);                // longest first within XCD stream
    const int bh = g + ((j >> 5) << 3);          // 8 bh per XCD
    const int bb = bh >> 4, hh = bh & 15;
    const unsigned short* Qp = Qb + (size_t)bh * T_SZ * D_SZ;
    const unsigned short* Kp = Kb + (size_t)bh * T_SZ * D_SZ;
    const unsigned short* Vp = Vt + (size_t)bh * T_SZ * D_SZ;  // [D=64][T=2048]
    const int tid = threadIdx.x, lane = tid & 63, wid = tid >> 6;
    const int l15 = lane & 15, lg = lane >> 4;
    const int rga = qb * 64 + wid * 16;

    __shared__ __align__(16) unsigned short Pl[4][16][72];  // per-wave P[q][key], padded

    // Q as B-fragment: B[col=q=l15][k=d]
    bf16x8 qf[2];
#pragma unroll
    for (int kh = 0; kh < 2; ++kh)
        qf[kh] = *(const bf16x8*)&Qp[(size_t)(rga + l15) * 64 + kh * 32 + lg * 8];

    f32x4 oacc[4] = {};
    float mreg = -1e30f, lreg = 0.f;   // per-lane stats for query rga + l15
    const int thr = wid * 16 + l15;    // local causal threshold at diagonal block

    // K as A-fragment: A[row=key=l15][k=d]
    bf16x8 kf[4][2];
#pragma unroll
    for (int ct = 0; ct < 4; ++ct)
#pragma unroll
        for (int kh = 0; kh < 2; ++kh)
            kf[ct][kh] = *(const bf16x8*)&Kp[(size_t)(ct * 16 + l15) * 64 + kh * 32 + lg * 8];

    for (int kb = 0; kb <= qb; ++kb) {
        const int k0 = kb * 64;
        // V for THIS block (B-frag from Vt): consumed at PV below; L2 latency
        // hidden under QK^T + softmax
        bf16x8 vf[4][2];
#pragma unroll
        for (int ct = 0; ct < 4; ++ct)
#pragma unroll
            for (int kh = 0; kh < 2; ++kh)
                vf[ct][kh] = *(const bf16x8*)&Vp[(size_t)(ct * 16 + l15) * 2048 + k0 + kh * 32 + lg * 8];

        // S^T = K Q^T : st[ct][i] = S[q=rga+l15][key=k0+ct*16+lg*4+i]
        f32x4 st[4];
#pragma unroll
        for (int ct = 0; ct < 4; ++ct) {
            f32x4 a = {};
            a = __builtin_amdgcn_mfma_f32_16x16x32_bf16(kf[ct][0], qf[0], a, 0, 0, 0);
            a = __builtin_amdgcn_mfma_f32_16x16x32_bf16(kf[ct][1], qf[1], a, 0, 0, 0);
            st[ct] = a;
        }
        // prefetch K(kb+1) into kf (anti-dep keeps it after the MFMAs above)
        if (kb < qb) {
#pragma unroll
            for (int ct = 0; ct < 4; ++ct)
#pragma unroll
                for (int kh = 0; kh < 2; ++kh)
                    kf[ct][kh] = *(const bf16x8*)&Kp[(size_t)(k0 + 64 + ct * 16 + l15) * 64 + kh * 32 + lg * 8];
        }
        // pin all loads above this point (prevent sinking into the uses)
        __builtin_amdgcn_sched_barrier(0);

        if (kb == qb) {  // diagonal: causal mask (exp2 domain, Q pre-scaled)
#pragma unroll
            for (int ct = 0; ct < 4; ++ct)
#pragma unroll
                for (int i = 0; i < 4; ++i)
                    if (ct * 16 + lg * 4 + i > thr) st[ct][i] = -1e30f;
        }

        // ---- per-lane softmax over this lane's 16 scores + 2 shfl steps ----
        float cm0 = fmaxf(fmaxf(st[0][0], st[0][1]), fmaxf(st[0][2], st[0][3]));
        float cm1 = fmaxf(fmaxf(st[1][0], st[1][1]), fmaxf(st[1][2], st[1][3]));
        float cm2 = fmaxf(fmaxf(st[2][0], st[2][1]), fmaxf(st[2][2], st[2][3]));
        float cm3 = fmaxf(fmaxf(st[3][0], st[3][1]), fmaxf(st[3][2], st[3][3]));
        float pmax = fmaxf(fmaxf(cm0, cm1), fmaxf(cm2, cm3));
        pmax = fmaxf(pmax, __shfl_xor(pmax, 16));
        pmax = fmaxf(pmax, __shfl_xor(pmax, 32));
        const float mnew = fmaxf(mreg, pmax);
        const float sc = __builtin_amdgcn_exp2f(mreg - mnew);
        mreg = mnew;
#pragma unroll
        for (int ct = 0; ct < 4; ++ct)
#pragma unroll
            for (int i = 0; i < 4; ++i)
                st[ct][i] = __builtin_amdgcn_exp2f(st[ct][i] - mnew);
        float cs0 = (st[0][0] + st[0][1]) + (st[0][2] + st[0][3]);
        float cs1 = (st[1][0] + st[1][1]) + (st[1][2] + st[1][3]);
        float cs2 = (st[2][0] + st[2][1]) + (st[2][2] + st[2][3]);
        float cs3 = (st[3][0] + st[3][1]) + (st[3][2] + st[3][3]);
        float psum = (cs0 + cs1) + (cs2 + cs3);
        psum += __shfl_xor(psum, 16);
        psum += __shfl_xor(psum, 32);
        lreg = lreg * sc + psum;

        // redistribute sc (query-indexed by l15) to O's row layout (q = lg*4+i)
        float scr[4];
#pragma unroll
        for (int i = 0; i < 4; ++i) scr[i] = __shfl(sc, lg * 4 + i, 16);
#pragma unroll
        for (int ct = 0; ct < 4; ++ct)
#pragma unroll
            for (int i = 0; i < 4; ++i) oacc[ct][i] *= scr[i];

        // P[q=l15][key] -> LDS: 4x ds_write_b64 (keys lg*4..lg*4+3 per ct-chunk)
#pragma unroll
        for (int ct = 0; ct < 4; ++ct) {
            unsigned int lo = (unsigned int)f2bf(st[ct][0]) | ((unsigned int)f2bf(st[ct][1]) << 16);
            unsigned int hi = (unsigned int)f2bf(st[ct][2]) | ((unsigned int)f2bf(st[ct][3]) << 16);
            uint2 u; u.x = lo; u.y = hi;
            *(uint2*)&Pl[wid][l15][ct * 16 + lg * 4] = u;
        }

        // O += P V : A-frag pf[row=q=l15][k=key], B-frag vf
#pragma unroll
        for (int kh = 0; kh < 2; ++kh) {
            const bf16x8 pf = *(const bf16x8*)&Pl[wid][l15][kh * 32 + lg * 8];
#pragma unroll
            for (int ct = 0; ct < 4; ++ct)
                oacc[ct] = __builtin_amdgcn_mfma_f32_16x16x32_bf16(pf, vf[ct][kh], oacc[ct], 0, 0, 0);
        }
    }

    // epilogue: redistribute l to row layout, divide, store
    float lr[4];
#pragma unroll
    for (int i = 0; i < 4; ++i) lr[i] = __shfl(lreg, lg * 4 + i, 16);
#pragma unroll
    for (int ct = 0; ct < 4; ++ct) {
#pragma unroll
        for (int i = 0; i < 4; ++i) {
            const int qrow = rga + lg * 4 + i;
            out[((size_t)bb * T_SZ + qrow) * C_SZ + hh * 64 + ct * 16 + l15] =
                oacc[ct][i] / lr[i];
        }
    }
}

extern "C" void kernel_launch(void* const* d_in, const int* in_sizes, int n_in,
                              void* d_out, int out_size, void* d_ws, size_t ws_size,
                              hipStream_t stream) {
    const float* x = (const float*)d_in[0];
    const float* w = (const float*)d_in[1];
    float* out = (float*)d_out;
    char* ws = (char*)d_ws;
    unsigned short* xb  = (unsigned short*)(ws);
    unsigned short* wtb = (unsigned short*)(ws + 16777216);
    unsigned short* Qb  = (unsigned short*)(ws + 16777216 + 6291456);
    unsigned short* Kb  = (unsigned short*)(ws + 16777216 + 6291456 + 16777216);
    unsigned short* Vtb = (unsigned short*)(ws + 16777216 + 6291456 + 2 * 16777216);

    k_convert<<<8192, 256, 0, stream>>>(x, xb, 2097152);
    k_transpose<<<dim3(96, 32), 256, 0, stream>>>(w, wtb);
    k_qkv_gemm<<<1536, 256, 0, stream>>>(xb, wtb, Qb, Kb, Vtb);
    k_attn<<<2048, 256, 0, stream>>>(Qb, Kb, Vtb, out);
}